// Round 6
// baseline (307.371 us; speedup 1.0000x reference)
//
#include <hip/hip_runtime.h>
#include <stdint.h>

typedef __bf16 bf16;
typedef __bf16 bf16x8 __attribute__((ext_vector_type(8)));
typedef __bf16 bf16x4_t __attribute__((ext_vector_type(4)));
typedef float f32x4 __attribute__((ext_vector_type(4)));

#define HQ_N 32
#define DH_N 64
#define SEQ 2048
#define NTOK 4096   // B*T

#if __has_builtin(__builtin_amdgcn_exp2f)
#define EXP2(x) __builtin_amdgcn_exp2f(x)
#else
#define EXP2(x) __expf((x) * 0.69314718056f)
#endif

// Q pre-scale folded into QKV epilogue: (1/sqrt(64)) * log2(e)
#define QSCALE 0.18033688011112042f

// ---- async global->LDS, 16B per lane ----
__device__ __forceinline__ void async_ld16(const bf16* g, bf16* l) {
    __builtin_amdgcn_global_load_lds(
        (__attribute__((address_space(1))) void*)(uintptr_t)(g),
        (__attribute__((address_space(3))) void*)(uint32_t)(uintptr_t)(l),
        16, 0, 0);
}

// ---- cast fp32 -> bf16, vectorized x4 ----
__global__ __launch_bounds__(256) void k_cast_bf16(const float* __restrict__ in,
                                                   bf16* __restrict__ out, int n4) {
    int i = blockIdx.x * 256 + threadIdx.x;
    if (i < n4) {
        float4 f = ((const float4*)in)[i];
        bf16x4_t v = {(bf16)f.x, (bf16)f.y, (bf16)f.z, (bf16)f.w};
        ((bf16x4_t*)out)[i] = v;
    }
}

// ---- all 4 weight transposes in one launch: z selects matrix ----
__global__ __launch_bounds__(256) void k_cast_transpose_all(
    const float* __restrict__ Wq, const float* __restrict__ Wk,
    const float* __restrict__ Wv, const float* __restrict__ Wo,
    bf16* __restrict__ WqkvT, bf16* __restrict__ WoT)
{
    const int z = blockIdx.z;
    const float* in; bf16* out; int C;
    const int R = 2048;
    if      (z == 0) { in = Wq; out = WqkvT;                        C = 2048; }
    else if (z == 1) { in = Wk; out = WqkvT + (size_t)2048 * 2048;  C = 512;  }
    else if (z == 2) { in = Wv; out = WqkvT + (size_t)2560 * 2048;  C = 512;  }
    else             { in = Wo; out = WoT;                          C = 2048; }
    if (blockIdx.x * 64 >= C) return;

    __shared__ float t[64][65];
    const int tid = threadIdx.x;
    const int c0 = blockIdx.x * 64, r0 = blockIdx.y * 64;
#pragma unroll
    for (int c = 0; c < 4; ++c) {
        int i = tid + c * 256;
        int row = i >> 4, cc = (i & 15) * 4;
        float4 v = *(const float4*)(in + (size_t)(r0 + row) * C + c0 + cc);
        t[row][cc + 0] = v.x; t[row][cc + 1] = v.y;
        t[row][cc + 2] = v.z; t[row][cc + 3] = v.w;
    }
    __syncthreads();
#pragma unroll
    for (int c = 0; c < 4; ++c) {
        int i = tid + c * 256;
        int row = i >> 4, cc = (i & 15) * 4;
        bf16x4_t v = {(bf16)t[cc + 0][row], (bf16)t[cc + 1][row],
                      (bf16)t[cc + 2][row], (bf16)t[cc + 3][row]};
        *(bf16x4_t*)(out + (size_t)(c0 + row) * R + r0 + cc) = v;
    }
}

// ---- bf16 MFMA GEMM: C[M][N] = A[M][K] * BT[N][K]^T ----
// 128x128 tile, 4 waves (2x2), each wave 4x4 of 16x16x32 MFMA.
// Software pipeline: BK=32 slabs, TWO LDS stages (2x16KB = 32KB), ONE barrier
// per slab. DMA for slab k+1 is issued right after the barrier and only
// consumed at the NEXT barrier -> a full compute phase of latency slack
// (the structural drain of the 2-barrier m97 shape is gone).
// LDS layout (per stage, per matrix): 128 rows x 32 cols, 16B chunks, logical
// chunk c stored at phys (c ^ (row&3) ^ ((row>>2)&3)) -> worst 2-way (free).
// mode 1: QKV epilogue; mode 2: fp32 out [M][ldc].
__global__ __launch_bounds__(256, 4) void k_gemm(
    const bf16* __restrict__ A, const bf16* __restrict__ BT,
    int lda, int ldb, int M, int N, int K, int mode,
    float* __restrict__ Cf, int ldc,
    bf16* __restrict__ Qb, bf16* __restrict__ Kb, bf16* __restrict__ VTb)
{
    __shared__ bf16 S[16384];        // 32 KiB: stage s at S + s*8192 (As | Bs)

    const int tid  = threadIdx.x;
    const int lane = tid & 63;
    const int w    = tid >> 6;
    const int l15  = lane & 15, quad = lane >> 4;
    const int wm = (w >> 1) * 64, wn = (w & 1) * 64;

    const int mb = M >> 7;
    const int band = blockIdx.x / (mb * 8);
    const int rsr  = blockIdx.x % (mb * 8);
    const int mi = rsr >> 3, ni = band * 8 + (rsr & 7);

    // staging geometry: slab = 128 rows x 32 k (8KB/matrix), slot i = tid+c*256:
    // row = i>>2 (c=1 adds 64 -> same &3 and >>2&3 bits), phys chunk = i&3
    const int srow0 = tid >> 2;
    const int lc = (tid & 3) ^ (srow0 & 3) ^ ((srow0 >> 2) & 3);
    const bf16* aP = A  + (size_t)(mi * 128 + srow0) * lda + lc * 8;
    const bf16* bP = BT + (size_t)(ni * 128 + srow0) * ldb + lc * 8;

    // fragment read offset (logical chunk = quad)
    const int ch = 8 * (quad ^ (l15 & 3) ^ (l15 >> 2));

    f32x4 acc[4][4] = {};

    // prologue: stage slab 0 into stage 0
    {
        bf16* As = S; bf16* Bs = S + 4096;
#pragma unroll
        for (int c = 0; c < 2; ++c) {
            async_ld16(aP + (size_t)c * 64 * lda, &As[(tid + c * 256) * 8]);
            async_ld16(bP + (size_t)c * 64 * ldb, &Bs[(tid + c * 256) * 8]);
        }
    }

    int st = 0;
    for (int k0 = 0; k0 < K; k0 += 32) {
        __syncthreads();   // drains slab-k0 DMA; all reads of the other stage done
        if (k0 + 32 < K) {
            bf16* An = S + ((st ^ 1) << 13);
            bf16* Bn = An + 4096;
#pragma unroll
            for (int c = 0; c < 2; ++c) {
                async_ld16(aP + (k0 + 32) + (size_t)c * 64 * lda, &An[(tid + c * 256) * 8]);
                async_ld16(bP + (k0 + 32) + (size_t)c * 64 * ldb, &Bn[(tid + c * 256) * 8]);
            }
        }
        const bf16* As = S + (st << 13);
        const bf16* Bs = As + 4096;
        bf16x8 af[4], bfr[4];
#pragma unroll
        for (int mt = 0; mt < 4; ++mt)
            af[mt] = *(const bf16x8*)(As + (wm + mt * 16 + l15) * 32 + ch);
#pragma unroll
        for (int nt = 0; nt < 4; ++nt)
            bfr[nt] = *(const bf16x8*)(Bs + (wn + nt * 16 + l15) * 32 + ch);
#pragma unroll
        for (int mt = 0; mt < 4; ++mt)
#pragma unroll
            for (int nt = 0; nt < 4; ++nt)
                acc[mt][nt] = __builtin_amdgcn_mfma_f32_16x16x32_bf16(
                    af[mt], bfr[nt], acc[mt][nt], 0, 0, 0);
        st ^= 1;
    }

    // epilogue: C/D layout col = lane&15, row = quad*4 + reg
    if (mode == 2) {
#pragma unroll
        for (int mt = 0; mt < 4; ++mt)
#pragma unroll
            for (int nt = 0; nt < 4; ++nt) {
                int rg0 = mi * 128 + wm + mt * 16 + quad * 4;
                int cg  = ni * 128 + wn + nt * 16 + l15;
#pragma unroll
                for (int r = 0; r < 4; ++r)
                    Cf[(size_t)(rg0 + r) * ldc + cg] = acc[mt][nt][r];
            }
    } else if (ni < 16) {            // Q block (cols 0..2047), pre-scaled
#pragma unroll
        for (int mt = 0; mt < 4; ++mt)
#pragma unroll
            for (int nt = 0; nt < 4; ++nt) {
                int rg0 = mi * 128 + wm + mt * 16 + quad * 4;
                int cg  = ni * 128 + wn + nt * 16 + l15;
#pragma unroll
                for (int r = 0; r < 4; ++r)
                    Qb[(size_t)(rg0 + r) * 2048 + cg] = (bf16)(acc[mt][nt][r] * QSCALE);
            }
    } else if (ni < 20) {            // K block (cols 2048..2559)
#pragma unroll
        for (int mt = 0; mt < 4; ++mt)
#pragma unroll
            for (int nt = 0; nt < 4; ++nt) {
                int rg0 = mi * 128 + wm + mt * 16 + quad * 4;
                int cg  = ni * 128 + wn + nt * 16 + l15 - 2048;
#pragma unroll
                for (int r = 0; r < 4; ++r)
                    Kb[(size_t)(rg0 + r) * 512 + cg] = (bf16)acc[mt][nt][r];
            }
    } else {                         // V block -> V^T via LDS bounce (coalesced)
        __syncthreads();
#pragma unroll
        for (int mt = 0; mt < 4; ++mt)
#pragma unroll
            for (int nt = 0; nt < 4; ++nt) {
                int rl0 = wm + mt * 16 + quad * 4;
                int cl  = wn + nt * 16 + l15;
#pragma unroll
                for (int r = 0; r < 4; ++r)
                    S[cl * 128 + rl0 + r] = (bf16)acc[mt][nt][r];
            }
        __syncthreads();
        const int v0 = ni * 128 - 2560;
#pragma unroll
        for (int c = 0; c < 8; ++c) {
            int i = tid + c * 256;
            int row = i >> 4, c8 = (i & 15) * 8;
            uint4 vv = *(const uint4*)(S + row * 128 + c8);
            *(uint4*)(VTb + (size_t)(v0 + row) * NTOK + mi * 128 + c8) = vv;
        }
    }
}

// ---- flash attention v5: double-buffered K/V, ONE barrier per K-tile ----
// Structure otherwise = proven v4: 256q block, 4 waves x 64q, 64-key tiles,
// Q frags in registers, S^T trick (b64 P writes), fixed-shift exp2 softmax,
// deferred l-reduction. LDS: Ks 2x8KB + Vt 2x8KB + Ps 32KB + Ls = 65KB.
__global__ __launch_bounds__(256, 2) void k_attn(
    const bf16* __restrict__ Qb,   // [4096][2048]  (pre-scaled)
    const bf16* __restrict__ Kb,   // [4096][512]
    const bf16* __restrict__ VTb,  // [512][4096]
    bf16* __restrict__ Ob)         // [4096][2048]
{
    __shared__ bf16 Ks[2][64 * 64];
    __shared__ bf16 Vt[2][64 * 64];
    __shared__ bf16 Ps[256 * 64];
    __shared__ float Ls[256];

    const int tid  = threadIdx.x;
    const int lane = tid & 63;
    const int w    = tid >> 6;
    const int l15  = lane & 15, quad = lane >> 4;
    const int l7   = l15 & 7;

    const int bid = blockIdx.x;          // 512 = 2 * 32 * 8
    const int qt  = bid & 7;
    const int hq  = (bid >> 3) & 31;
    const int b   = bid >> 8;
    const int hkv = hq >> 2;             // GROUP = 4
    const int q0  = qt * 256;
    const int wq0 = w * 64;
    const size_t tokbase = (size_t)b * SEQ;

    bf16* Pw = Ps + w * (64 * 64);

    // staging pointers (swizzled source, per-lane constant)
    const int srow = tid >> 3;                       // 0..31
    const int sc8e = ((tid & 7) ^ (srow & 7)) * 8;
    const bf16* kP = Kb  + (tokbase + srow) * 512 + hkv * DH_N + sc8e;
    const bf16* vP = VTb + ((size_t)hkv * DH_N + srow) * NTOK + tokbase + sc8e;

    // Q fragments in registers
    bf16x8 qf[4][2];
#pragma unroll
    for (int nt = 0; nt < 4; ++nt)
#pragma unroll
        for (int ks = 0; ks < 2; ++ks)
            qf[nt][ks] = *(const bf16x8*)(
                Qb + (tokbase + q0 + wq0 + nt * 16 + l15) * 2048 + hq * DH_N + ks * 32 + quad * 8);

    f32x4 acc_o[4][4] = {};
    float lsum[4] = {0.f, 0.f, 0.f, 0.f};

    // prologue: stage tile 0 into buffer 0
#pragma unroll
    for (int c = 0; c < 2; ++c) {
        async_ld16(kP + (size_t)c * 32 * 512,  &Ks[0][(tid + c * 256) * 8]);
        async_ld16(vP + (size_t)c * 32 * NTOK, &Vt[0][(tid + c * 256) * 8]);
    }
    kP += 64 * 512;
    vP += 64;

    int st = 0;
    for (int kt = 0; kt < 32; ++kt) {
        __syncthreads();   // drains tile-kt DMA; all reads of buffer st^1 done
        if (kt + 1 < 32) {
#pragma unroll
            for (int c = 0; c < 2; ++c) {
                async_ld16(kP + (size_t)c * 32 * 512,  &Ks[st ^ 1][(tid + c * 256) * 8]);
                async_ld16(vP + (size_t)c * 32 * NTOK, &Vt[st ^ 1][(tid + c * 256) * 8]);
            }
            kP += 64 * 512;
            vP += 64;
        }

        // St = K * Q^T : C[m=key][n=q], wave computes [64 key][64 q]
        f32x4 accs[4][4] = {};
#pragma unroll
        for (int ks = 0; ks < 2; ++ks) {
            const int ch = 8 * (((ks << 2) | quad) ^ l7);
            bf16x8 kf[4];
#pragma unroll
            for (int mt = 0; mt < 4; ++mt)
                kf[mt] = *(const bf16x8*)(&Ks[st][0] + (mt * 16 + l15) * 64 + ch);
#pragma unroll
            for (int mt = 0; mt < 4; ++mt)
#pragma unroll
                for (int nt = 0; nt < 4; ++nt)
                    accs[mt][nt] = __builtin_amdgcn_mfma_f32_16x16x32_bf16(
                        kf[mt], qf[nt][ks], accs[mt][nt], 0, 0, 0);
        }

        // softmax: p = exp2(st); lane holds 4 consecutive keys of one q-row
#pragma unroll
        for (int mt = 0; mt < 4; ++mt) {
            const int wch = (mt * 2 + (quad >> 1));
            const int sub = (quad & 1) * 4;
#pragma unroll
            for (int nt = 0; nt < 4; ++nt) {
                float p0 = EXP2(accs[mt][nt][0]);
                float p1 = EXP2(accs[mt][nt][1]);
                float p2 = EXP2(accs[mt][nt][2]);
                float p3 = EXP2(accs[mt][nt][3]);
                lsum[nt] += (p0 + p1) + (p2 + p3);
                bf16x4_t pv = {(bf16)p0, (bf16)p1, (bf16)p2, (bf16)p3};
                *(bf16x4_t*)&Pw[(nt * 16 + l15) * 64 + 8 * (wch ^ l7) + sub] = pv;
            }
        }

        // O += P * V  (P rows wave-private)
#pragma unroll
        for (int ks = 0; ks < 2; ++ks) {
            const int ch = 8 * (((ks << 2) | quad) ^ l7);
            bf16x8 pf[4], vf[4];
#pragma unroll
            for (int mt = 0; mt < 4; ++mt)
                pf[mt] = *(const bf16x8*)(Pw + (mt * 16 + l15) * 64 + ch);
#pragma unroll
            for (int nt = 0; nt < 4; ++nt)
                vf[nt] = *(const bf16x8*)(&Vt[st][0] + (nt * 16 + l15) * 64 + ch);
#pragma unroll
            for (int mt = 0; mt < 4; ++mt)
#pragma unroll
                for (int nt = 0; nt < 4; ++nt)
                    acc_o[mt][nt] = __builtin_amdgcn_mfma_f32_16x16x32_bf16(
                        pf[mt], vf[nt], acc_o[mt][nt], 0, 0, 0);
        }
        st ^= 1;
    }

    // reduce l across the 4 quads, store reciprocal
#pragma unroll
    for (int nt = 0; nt < 4; ++nt) {
        float s = lsum[nt];
        s += __shfl_xor(s, 16);
        s += __shfl_xor(s, 32);
        Ls[w * 64 + nt * 16 + l15] = 1.0f / s;
    }

    // epilogue: O *= 1/l, write bf16 [token][hq*64 + d]
#pragma unroll
    for (int mt = 0; mt < 4; ++mt) {
#pragma unroll
        for (int r = 0; r < 4; ++r) {
            float rl = Ls[w * 64 + mt * 16 + quad * 4 + r];
            int qrow = q0 + wq0 + mt * 16 + quad * 4 + r;
#pragma unroll
            for (int nt = 0; nt < 4; ++nt) {
                float v = acc_o[mt][nt][r] * rl;
                Ob[(tokbase + qrow) * 2048 + hq * DH_N + nt * 16 + l15] = (bf16)v;
            }
        }
    }
}

extern "C" void kernel_launch(void* const* d_in, const int* in_sizes, int n_in,
                              void* d_out, int out_size, void* d_ws, size_t ws_size,
                              hipStream_t stream)
{
    const float* x  = (const float*)d_in[0];
    const float* Wq = (const float*)d_in[1];
    const float* Wk = (const float*)d_in[2];
    const float* Wv = (const float*)d_in[3];
    const float* Wo = (const float*)d_in[4];
    float* out = (float*)d_out;

    // workspace layout (bf16 elements), ~80 MB total
    bf16* ws    = (bf16*)d_ws;
    bf16* xb    = ws;                              // [4096][2048]
    bf16* WqkvT = xb    + (size_t)4096 * 2048;     // [3072][2048]  (Wq^T | Wk^T | Wv^T)
    bf16* WoT   = WqkvT + (size_t)3072 * 2048;     // [2048][2048]
    bf16* Qb    = WoT   + (size_t)2048 * 2048;     // [4096][2048]
    bf16* Kb    = Qb    + (size_t)4096 * 2048;     // [4096][512]
    bf16* VTb   = Kb    + (size_t)4096 * 512;      // [512][4096]
    bf16* Ob    = VTb   + (size_t)512 * 4096;      // [4096][2048]

    k_cast_bf16<<<8192, 256, 0, stream>>>(x, xb, 4096 * 2048 / 4);
    k_cast_transpose_all<<<dim3(32, 32, 4), 256, 0, stream>>>(
        Wq, Wk, Wv, Wo, WqkvT, WoT);

    // fused QKV projection: [4096,2048] x [2048,3072]
    k_gemm<<<(4096 / 128) * (3072 / 128), 256, 0, stream>>>(
        xb, WqkvT, 2048, 2048, 4096, 3072, 2048, 1,
        nullptr, 0, Qb, Kb, VTb);

    // flash attention: 2 * 32 heads * 8 q-tiles of 256 rows
    k_attn<<<512, 256, 0, stream>>>(Qb, Kb, VTb, Ob);

    // output projection -> fp32 d_out
    k_gemm<<<(4096 / 128) * (2048 / 128), 256, 0, stream>>>(
        Ob, WoT, 2048, 2048, 4096, 2048, 2048, 2,
        out, 2048, nullptr, nullptr, nullptr);
}

// Round 7
// 295.338 us; speedup vs baseline: 1.0407x; 1.0407x over previous
//
#include <hip/hip_runtime.h>
#include <stdint.h>

typedef __bf16 bf16;
typedef __bf16 bf16x8 __attribute__((ext_vector_type(8)));
typedef __bf16 bf16x4_t __attribute__((ext_vector_type(4)));
typedef float f32x4 __attribute__((ext_vector_type(4)));

#define HQ_N 32
#define DH_N 64
#define SEQ 2048
#define NTOK 4096   // B*T

#if __has_builtin(__builtin_amdgcn_exp2f)
#define EXP2(x) __builtin_amdgcn_exp2f(x)
#else
#define EXP2(x) __expf((x) * 0.69314718056f)
#endif

// Q pre-scale folded into QKV epilogue: (1/sqrt(64)) * log2(e)
#define QSCALE 0.18033688011112042f

// ---- async global->LDS, 16B per lane ----
__device__ __forceinline__ void async_ld16(const bf16* g, bf16* l) {
    __builtin_amdgcn_global_load_lds(
        (__attribute__((address_space(1))) void*)(uintptr_t)(g),
        (__attribute__((address_space(3))) void*)(uint32_t)(uintptr_t)(l),
        16, 0, 0);
}

// ---- fused prep: z<4 -> weight cast+transpose (64x64 tiles); z>=4 -> x cast ----
__global__ __launch_bounds__(256) void k_prep(
    const float* __restrict__ x,
    const float* __restrict__ Wq, const float* __restrict__ Wk,
    const float* __restrict__ Wv, const float* __restrict__ Wo,
    bf16* __restrict__ xb, bf16* __restrict__ WqkvT, bf16* __restrict__ WoT)
{
    const int z = blockIdx.z;
    const int tid = threadIdx.x;

    if (z >= 4) {   // cast x: 8 z-slices x 1024 blocks x 256 thr x 1 float4
        int i = ((z - 4) * 1024 + blockIdx.y * 32 + blockIdx.x) * 256 + tid;
        float4 f = ((const float4*)x)[i];
        bf16x4_t v = {(bf16)f.x, (bf16)f.y, (bf16)f.z, (bf16)f.w};
        ((bf16x4_t*)xb)[i] = v;
        return;
    }

    const float* in; bf16* out; int C;
    const int R = 2048;
    if      (z == 0) { in = Wq; out = WqkvT;                        C = 2048; }
    else if (z == 1) { in = Wk; out = WqkvT + (size_t)2048 * 2048;  C = 512;  }
    else if (z == 2) { in = Wv; out = WqkvT + (size_t)2560 * 2048;  C = 512;  }
    else             { in = Wo; out = WoT;                          C = 2048; }
    if (blockIdx.x * 64 >= C) return;

    __shared__ float t[64][65];
    const int c0 = blockIdx.x * 64, r0 = blockIdx.y * 64;
#pragma unroll
    for (int c = 0; c < 4; ++c) {
        int i = tid + c * 256;
        int row = i >> 4, cc = (i & 15) * 4;
        float4 v = *(const float4*)(in + (size_t)(r0 + row) * C + c0 + cc);
        t[row][cc + 0] = v.x; t[row][cc + 1] = v.y;
        t[row][cc + 2] = v.z; t[row][cc + 3] = v.w;
    }
    __syncthreads();
#pragma unroll
    for (int c = 0; c < 4; ++c) {
        int i = tid + c * 256;
        int row = i >> 4, cc = (i & 15) * 4;
        bf16x4_t v = {(bf16)t[cc + 0][row], (bf16)t[cc + 1][row],
                      (bf16)t[cc + 2][row], (bf16)t[cc + 3][row]};
        *(bf16x4_t*)(out + (size_t)(c0 + row) * R + r0 + cc) = v;
    }
}

// ---- bf16 MFMA GEMM (R5-proven): 128x128 tile, BK=64, 2-barrier K-loop ----
// DMA-source XOR swizzle at 16B granularity; supertile remap for L2.
// mode 1: QKV epilogue; mode 2: fp32 out.
__global__ __launch_bounds__(256, 3) void k_gemm(
    const bf16* __restrict__ A, const bf16* __restrict__ BT,
    int lda, int ldb, int M, int N, int K, int mode,
    float* __restrict__ Cf, int ldc,
    bf16* __restrict__ Qb, bf16* __restrict__ Kb, bf16* __restrict__ VTb)
{
    __shared__ bf16 S[16384];        // 32 KiB: As | Bs  (also V^T bounce buffer)
    bf16* As = S;
    bf16* Bs = S + 8192;

    const int tid  = threadIdx.x;
    const int lane = tid & 63;
    const int w    = tid >> 6;
    const int l15  = lane & 15, quad = lane >> 4;
    const int l7   = l15 & 7;
    const int wm = (w >> 1) * 64, wn = (w & 1) * 64;

    const int mb = M >> 7;
    const int band = blockIdx.x / (mb * 8);
    const int rsr  = blockIdx.x % (mb * 8);
    const int mi = rsr >> 3, ni = band * 8 + (rsr & 7);

    const int srow = tid >> 3;                       // 0..31
    const int sc8e = ((tid & 7) ^ (srow & 7)) * 8;   // swizzled logical chunk
    const bf16* aP = A  + (size_t)(mi * 128 + srow) * lda + sc8e;
    const bf16* bP = BT + (size_t)(ni * 128 + srow) * ldb + sc8e;

    f32x4 acc[4][4] = {};

    for (int k0 = 0; k0 < K; k0 += 64) {
        __syncthreads();
#pragma unroll
        for (int c = 0; c < 4; ++c) {
            async_ld16(aP + (size_t)c * 32 * lda, &As[(tid + c * 256) * 8]);
            async_ld16(bP + (size_t)c * 32 * ldb, &Bs[(tid + c * 256) * 8]);
        }
        aP += 64; bP += 64;
        __syncthreads();
#pragma unroll
        for (int ks = 0; ks < 2; ++ks) {
            const int ch = 8 * (((ks << 2) | quad) ^ l7);
            bf16x8 af[4], bfr[4];
#pragma unroll
            for (int mt = 0; mt < 4; ++mt)
                af[mt] = *(const bf16x8*)(As + (wm + mt * 16 + l15) * 64 + ch);
#pragma unroll
            for (int nt = 0; nt < 4; ++nt)
                bfr[nt] = *(const bf16x8*)(Bs + (wn + nt * 16 + l15) * 64 + ch);
#pragma unroll
            for (int mt = 0; mt < 4; ++mt)
#pragma unroll
                for (int nt = 0; nt < 4; ++nt)
                    acc[mt][nt] = __builtin_amdgcn_mfma_f32_16x16x32_bf16(
                        af[mt], bfr[nt], acc[mt][nt], 0, 0, 0);
        }
    }

    // epilogue: C/D layout col = lane&15, row = quad*4 + reg
    if (mode == 2) {
#pragma unroll
        for (int mt = 0; mt < 4; ++mt)
#pragma unroll
            for (int nt = 0; nt < 4; ++nt) {
                int rg0 = mi * 128 + wm + mt * 16 + quad * 4;
                int cg  = ni * 128 + wn + nt * 16 + l15;
#pragma unroll
                for (int r = 0; r < 4; ++r)
                    Cf[(size_t)(rg0 + r) * ldc + cg] = acc[mt][nt][r];
            }
    } else if (ni < 16) {            // Q block (cols 0..2047), pre-scaled
#pragma unroll
        for (int mt = 0; mt < 4; ++mt)
#pragma unroll
            for (int nt = 0; nt < 4; ++nt) {
                int rg0 = mi * 128 + wm + mt * 16 + quad * 4;
                int cg  = ni * 128 + wn + nt * 16 + l15;
#pragma unroll
                for (int r = 0; r < 4; ++r)
                    Qb[(size_t)(rg0 + r) * 2048 + cg] = (bf16)(acc[mt][nt][r] * QSCALE);
            }
    } else if (ni < 20) {            // K block (cols 2048..2559)
#pragma unroll
        for (int mt = 0; mt < 4; ++mt)
#pragma unroll
            for (int nt = 0; nt < 4; ++nt) {
                int rg0 = mi * 128 + wm + mt * 16 + quad * 4;
                int cg  = ni * 128 + wn + nt * 16 + l15 - 2048;
#pragma unroll
                for (int r = 0; r < 4; ++r)
                    Kb[(size_t)(rg0 + r) * 512 + cg] = (bf16)acc[mt][nt][r];
            }
    } else {                         // V block -> V^T via LDS bounce (coalesced)
        __syncthreads();
#pragma unroll
        for (int mt = 0; mt < 4; ++mt)
#pragma unroll
            for (int nt = 0; nt < 4; ++nt) {
                int rl0 = wm + mt * 16 + quad * 4;
                int cl  = wn + nt * 16 + l15;
#pragma unroll
                for (int r = 0; r < 4; ++r)
                    S[cl * 128 + rl0 + r] = (bf16)acc[mt][nt][r];
            }
        __syncthreads();
        const int v0 = ni * 128 - 2560;
#pragma unroll
        for (int c = 0; c < 8; ++c) {
            int i = tid + c * 256;
            int row = i >> 4, c8 = (i & 15) * 8;
            uint4 vv = *(const uint4*)(S + row * 128 + c8);
            *(uint4*)(VTb + (size_t)(v0 + row) * NTOK + mi * 128 + c8) = vv;
        }
    }
}

// ---- flash attention v6 ----
// = proven v4 (R5) structure: single-buffered K/V (dbuf measured neutral),
// 256q block / 4 waves x 64q, 64-key tiles, Q frags in registers, S^T trick,
// fixed-shift exp2 softmax, deferred l-reduce.
// CHANGE vs R5: Ps rows stride 72 elem (144 B = 4-bank rotation/row) with NO
// XOR — removes the b64 P-write 4-way alias (was 4.19e6 conflict cycles).
__global__ __launch_bounds__(256, 2) void k_attn(
    const bf16* __restrict__ Qb,   // [4096][2048]  (pre-scaled)
    const bf16* __restrict__ Kb,   // [4096][512]
    const bf16* __restrict__ VTb,  // [512][4096]
    bf16* __restrict__ Ob)         // [4096][2048]
{
    __shared__ bf16 Ks[64 * 64];
    __shared__ bf16 Vt[64 * 64];
    __shared__ bf16 Ps[4 * 64 * 72];
    __shared__ float Ls[256];

    const int tid  = threadIdx.x;
    const int lane = tid & 63;
    const int w    = tid >> 6;
    const int l15  = lane & 15, quad = lane >> 4;
    const int l7   = l15 & 7;

    const int bid = blockIdx.x;          // 512 = 2 * 32 * 8
    const int qt  = bid & 7;
    const int hq  = (bid >> 3) & 31;
    const int b   = bid >> 8;
    const int hkv = hq >> 2;             // GROUP = 4
    const int q0  = qt * 256;
    const int wq0 = w * 64;
    const size_t tokbase = (size_t)b * SEQ;

    bf16* Pw = Ps + w * (64 * 72);

    // staging pointers (swizzled source, per-lane constant)
    const int srow = tid >> 3;                       // 0..31
    const int sc8e = ((tid & 7) ^ (srow & 7)) * 8;
    const bf16* kP = Kb  + (tokbase + srow) * 512 + hkv * DH_N + sc8e;
    const bf16* vP = VTb + ((size_t)hkv * DH_N + srow) * NTOK + tokbase + sc8e;

    // Q fragments in registers
    bf16x8 qf[4][2];
#pragma unroll
    for (int nt = 0; nt < 4; ++nt)
#pragma unroll
        for (int ks = 0; ks < 2; ++ks)
            qf[nt][ks] = *(const bf16x8*)(
                Qb + (tokbase + q0 + wq0 + nt * 16 + l15) * 2048 + hq * DH_N + ks * 32 + quad * 8);

    f32x4 acc_o[4][4] = {};
    float lsum[4] = {0.f, 0.f, 0.f, 0.f};

    for (int kt = 0; kt < 32; ++kt) {
        const int k0 = kt * 64;
        __syncthreads();   // prior iter's K/V reads done
#pragma unroll
        for (int c = 0; c < 2; ++c) {
            async_ld16(kP + (size_t)(k0 + c * 32) * 512, &Ks[(tid + c * 256) * 8]);
            async_ld16(vP + k0 + (size_t)c * 32 * NTOK,  &Vt[(tid + c * 256) * 8]);
        }
        __syncthreads();

        // St = K * Q^T : C[m=key][n=q], wave computes [64 key][64 q]
        f32x4 accs[4][4] = {};
#pragma unroll
        for (int ks = 0; ks < 2; ++ks) {
            const int ch = 8 * (((ks << 2) | quad) ^ l7);
            bf16x8 kf[4];
#pragma unroll
            for (int mt = 0; mt < 4; ++mt)
                kf[mt] = *(const bf16x8*)(Ks + (mt * 16 + l15) * 64 + ch);
#pragma unroll
            for (int mt = 0; mt < 4; ++mt)
#pragma unroll
                for (int nt = 0; nt < 4; ++nt)
                    accs[mt][nt] = __builtin_amdgcn_mfma_f32_16x16x32_bf16(
                        kf[mt], qf[nt][ks], accs[mt][nt], 0, 0, 0);
        }

        // softmax: p = exp2(st); lane holds keys mt*16+quad*4..+3 of q-row
        // nt*16+l15 -> one b64 write, plain layout (stride-72 rotates banks)
#pragma unroll
        for (int mt = 0; mt < 4; ++mt) {
#pragma unroll
            for (int nt = 0; nt < 4; ++nt) {
                float p0 = EXP2(accs[mt][nt][0]);
                float p1 = EXP2(accs[mt][nt][1]);
                float p2 = EXP2(accs[mt][nt][2]);
                float p3 = EXP2(accs[mt][nt][3]);
                lsum[nt] += (p0 + p1) + (p2 + p3);
                bf16x4_t pv = {(bf16)p0, (bf16)p1, (bf16)p2, (bf16)p3};
                *(bf16x4_t*)&Pw[(nt * 16 + l15) * 72 + mt * 16 + quad * 4] = pv;
            }
        }

        // O += P * V  (P rows wave-private; in-wave lgkmcnt ordering suffices)
#pragma unroll
        for (int ks = 0; ks < 2; ++ks) {
            const int chv = 8 * (((ks << 2) | quad) ^ l7);
            const int chp = ks * 32 + quad * 8;
            bf16x8 pf[4], vf[4];
#pragma unroll
            for (int mt = 0; mt < 4; ++mt)
                pf[mt] = *(const bf16x8*)(Pw + (mt * 16 + l15) * 72 + chp);
#pragma unroll
            for (int nt = 0; nt < 4; ++nt)
                vf[nt] = *(const bf16x8*)(Vt + (nt * 16 + l15) * 64 + chv);
#pragma unroll
            for (int mt = 0; mt < 4; ++mt)
#pragma unroll
                for (int nt = 0; nt < 4; ++nt)
                    acc_o[mt][nt] = __builtin_amdgcn_mfma_f32_16x16x32_bf16(
                        pf[mt], vf[nt], acc_o[mt][nt], 0, 0, 0);
        }
    }

    // reduce l across the 4 quads, store reciprocal
#pragma unroll
    for (int nt = 0; nt < 4; ++nt) {
        float s = lsum[nt];
        s += __shfl_xor(s, 16);
        s += __shfl_xor(s, 32);
        Ls[w * 64 + nt * 16 + l15] = 1.0f / s;
    }

    // epilogue: O *= 1/l, write bf16 [token][hq*64 + d]
#pragma unroll
    for (int mt = 0; mt < 4; ++mt) {
#pragma unroll
        for (int r = 0; r < 4; ++r) {
            float rl = Ls[w * 64 + mt * 16 + quad * 4 + r];
            int qrow = q0 + wq0 + mt * 16 + quad * 4 + r;
#pragma unroll
            for (int nt = 0; nt < 4; ++nt) {
                float v = acc_o[mt][nt][r] * rl;
                Ob[(tokbase + qrow) * 2048 + hq * DH_N + nt * 16 + l15] = (bf16)v;
            }
        }
    }
}

extern "C" void kernel_launch(void* const* d_in, const int* in_sizes, int n_in,
                              void* d_out, int out_size, void* d_ws, size_t ws_size,
                              hipStream_t stream)
{
    const float* x  = (const float*)d_in[0];
    const float* Wq = (const float*)d_in[1];
    const float* Wk = (const float*)d_in[2];
    const float* Wv = (const float*)d_in[3];
    const float* Wo = (const float*)d_in[4];
    float* out = (float*)d_out;

    // workspace layout (bf16 elements), ~80 MB total
    bf16* ws    = (bf16*)d_ws;
    bf16* xb    = ws;                              // [4096][2048]
    bf16* WqkvT = xb    + (size_t)4096 * 2048;     // [3072][2048]  (Wq^T | Wk^T | Wv^T)
    bf16* WoT   = WqkvT + (size_t)3072 * 2048;     // [2048][2048]
    bf16* Qb    = WoT   + (size_t)2048 * 2048;     // [4096][2048]
    bf16* Kb    = Qb    + (size_t)4096 * 2048;     // [4096][512]
    bf16* VTb   = Kb    + (size_t)4096 * 512;      // [512][4096]
    bf16* Ob    = VTb   + (size_t)512 * 4096;      // [4096][2048]

    // fused prep: z 0..3 weight transposes, z 4..11 x cast
    k_prep<<<dim3(32, 32, 12), 256, 0, stream>>>(
        x, Wq, Wk, Wv, Wo, xb, WqkvT, WoT);

    // fused QKV projection: [4096,2048] x [2048,3072]
    k_gemm<<<(4096 / 128) * (3072 / 128), 256, 0, stream>>>(
        xb, WqkvT, 2048, 2048, 4096, 3072, 2048, 1,
        nullptr, 0, Qb, Kb, VTb);

    // flash attention: 2 * 32 heads * 8 q-tiles of 256 rows
    k_attn<<<512, 256, 0, stream>>>(Qb, Kb, VTb, Ob);

    // output projection -> fp32 d_out
    k_gemm<<<(4096 / 128) * (2048 / 128), 256, 0, stream>>>(
        Ob, WoT, 2048, 2048, 4096, 2048, 2048, 2,
        out, 2048, nullptr, nullptr, nullptr);
}